// Round 5
// baseline (469.162 us; speedup 1.0000x reference)
//
#include <hip/hip_runtime.h>
#include <stdint.h>

// NODE forest — bit-exact replication of the harness's numpy float32 reference.
// Evidence: all-f64 decisions (r3, r4) give identical absmax 0.699 -> np ref is
// f32. Two f32 semantics to match:
//  (1) np.einsum('bi,tdi->btd') f32 order: baseline-SIMD SSE (vstep=4, no FMA),
//      reverse-chained muladd blocks, SSE3 hadd reduce (s0+s1)+(s2+s3), then a
//      separate f32 bias add.
//  (2) sigmoid(z)>0.5 in f32: 1/(1+expf(-z)) == 0.5 exactly for 0<z<=1.5*2^-24
//      (expf correctly rounded near 0) -> bit = (z > 1.5*2^-24).
// fp contract OFF so mul+add stay separate (numpy baseline has no FMA).

typedef float f32x4 __attribute__((ext_vector_type(4)));
typedef float f32x2 __attribute__((ext_vector_type(2)));

static constexpr int kRows   = 1048576;
static constexpr int kBlocks = 2048;
static constexpr int kWaves  = 4;   // 256 threads/block
static constexpr int kChunks = kRows / 64 / (kBlocks * kWaves); // = 2
static constexpr float kTau  = 1.5f * 0x1p-24f;  // f32 sigmoid dead-zone edge

__global__ __launch_bounds__(256) void forest_np32(
    const float* __restrict__ x,     // [B,64]
    const float* __restrict__ Wsel,  // [48,64]  row d = (tree d/6, level d%6)
    const float* __restrict__ bsel,  // [48]
    const float* __restrict__ leaf,  // [8,64,2]
    const float* __restrict__ fcw,   // [2,16]
    const float* __restrict__ fcb,   // [2]
    float* __restrict__ out)         // [B,2]
{
#pragma clang fp contract(off)
  __shared__ f32x2 lleaf[512];
  ((f32x4*)lleaf)[threadIdx.x] = ((const f32x4*)leaf)[threadIdx.x];
  __syncthreads();

  const int lane = threadIdx.x & 63;
  const int wave = threadIdx.x >> 6;
  const int wid  = blockIdx.x * kWaves + wave;

  for (int it = 0; it < kChunks; ++it) {
    const int    row = (wid * kChunks + it) * 64 + lane;
    const f32x4* xp  = (const f32x4*)(x + (size_t)row * 64);

    float xr[64];
#pragma unroll
    for (int q = 0; q < 16; ++q) {
      const f32x4 v = xp[q];
      xr[4 * q + 0] = v.x; xr[4 * q + 1] = v.y;
      xr[4 * q + 2] = v.z; xr[4 * q + 3] = v.w;
    }

    uint64_t bits = 0;
#pragma unroll 2
    for (int d = 0; d < 48; ++d) {
      const float* __restrict__ w = Wsel + d * 64;  // wave-uniform -> s_load
      // numpy SSE einsum: lane L accumulates elements {16j + {12,8,4,0} + L}
      // serially (reverse-chained npyv_muladd, mul and add rounded separately).
      float s[4];
#pragma unroll
      for (int L = 0; L < 4; ++L) {
        float t = xr[12 + L] * w[12 + L];        // + vaccum(=0), exact
        t = xr[8 + L] * w[8 + L] + t;
        t = xr[4 + L] * w[4 + L] + t;
        t = xr[0 + L] * w[0 + L] + t;
#pragma unroll
        for (int j = 1; j < 4; ++j) {
          const int o = 16 * j;
          t = xr[o + 12 + L] * w[o + 12 + L] + t;
          t = xr[o +  8 + L] * w[o +  8 + L] + t;
          t = xr[o +  4 + L] * w[o +  4 + L] + t;
          t = xr[o +  0 + L] * w[o +  0 + L] + t;
        }
        s[L] = t;
      }
      const float dot = (s[0] + s[1]) + (s[2] + s[3]);  // SSE3 hadd pairing
      const float z   = dot + bsel[d];                  // separate np bias add
      bits |= (uint64_t)(z > kTau ? 1u : 0u) << d;
    }

    // Tree walk (level 0 = MSB), LDS leaf gather, 16->2 FC (f32; any order
    // differs from np's sgemm by <= 1 bf16 ulp -- far under threshold).
    float o0 = fcb[0], o1 = fcb[1];
#pragma unroll
    for (int t = 0; t < 8; ++t) {
      int idx = 0;
#pragma unroll
      for (int l = 0; l < 6; ++l)
        idx = idx * 2 + (int)((bits >> (t * 6 + l)) & 1u);
      const f32x2 lv = lleaf[t * 64 + idx];
      o0 = fmaf(lv.x, fcw[2 * t], o0);
      o0 = fmaf(lv.y, fcw[2 * t + 1], o0);
      o1 = fmaf(lv.x, fcw[16 + 2 * t], o1);
      o1 = fmaf(lv.y, fcw[16 + 2 * t + 1], o1);
    }
    f32x2 r; r.x = o0; r.y = o1;
    ((f32x2*)out)[row] = r;
  }
}

extern "C" void kernel_launch(void* const* d_in, const int* in_sizes, int n_in,
                              void* d_out, int out_size, void* d_ws, size_t ws_size,
                              hipStream_t stream) {
  (void)in_sizes; (void)n_in; (void)out_size; (void)d_ws; (void)ws_size;
  forest_np32<<<kBlocks, 256, 0, stream>>>(
      (const float*)d_in[0],   // x
      (const float*)d_in[1],   // W_sel
      (const float*)d_in[2],   // b_sel
      (const float*)d_in[3],   // leaf_values
      (const float*)d_in[4],   // fc_w
      (const float*)d_in[5],   // fc_b
      (float*)d_out);
}

// Round 6
// 423.406 us; speedup vs baseline: 1.1081x; 1.1081x over previous
//
#include <hip/hip_runtime.h>
#include <stdint.h>

// NODE forest — fast path + np-exact fixup.
// Verified semantics (round 5 PASS): decision bit d of a row is
//   z_np > tau,  tau = 1.5*2^-24  (f32 sigmoid dead-zone: 1/(1+expf(-z))==0.5)
// where z_np = numpy-SSE-ordered f32 dot (no FMA, reverse-chained muladd,
// hadd pairing) + bias. Fast path computes z with packed f32 FMA (any order);
// only logits with |z_fast - tau| < 1e-4 (>=20x the max inter-order drift)
// take the bit-exact np-order recompute (~4K rows/1M, per-d divergent).

typedef float f32x2 __attribute__((ext_vector_type(2)));
typedef float f32x4 __attribute__((ext_vector_type(4)));

static constexpr int   kBlocks  = 4096;   // x 4 waves x 64 lanes x 1 row-chunk = 1M rows
static constexpr float kTau     = 1.5f * 0x1p-24f;
static constexpr float kMargin  = 1e-4f;

// Bit-exact replica of numpy's baseline-SIMD einsum f32 order (round-5 code).
__device__ __noinline__ float np_exact_dot(const float* __restrict__ xs,
                                           const float* __restrict__ w) {
#pragma clang fp contract(off)
  float s[4];
#pragma unroll
  for (int L = 0; L < 4; ++L) {
    float t = xs[12 + L] * w[12 + L];
    t = xs[8 + L] * w[8 + L] + t;
    t = xs[4 + L] * w[4 + L] + t;
    t = xs[0 + L] * w[0 + L] + t;
#pragma unroll
    for (int j = 1; j < 4; ++j) {
      const int o = 16 * j;
      t = xs[o + 12 + L] * w[o + 12 + L] + t;
      t = xs[o +  8 + L] * w[o +  8 + L] + t;
      t = xs[o +  4 + L] * w[o +  4 + L] + t;
      t = xs[o +  0 + L] * w[o +  0 + L] + t;
    }
    s[L] = t;
  }
  return (s[0] + s[1]) + (s[2] + s[3]);   // SSE3 hadd pairing
}

__global__ __launch_bounds__(256) void forest_fast(
    const float* __restrict__ x,     // [B,64]
    const float* __restrict__ Wsel,  // [48,64]
    const float* __restrict__ bsel,  // [48]
    const float* __restrict__ leaf,  // [8,64,2]
    const float* __restrict__ fcw,   // [2,16]
    const float* __restrict__ fcb,   // [2]
    float* __restrict__ out)         // [B,2]
{
  __shared__ f32x2 lleaf[512];
  ((f32x4*)lleaf)[threadIdx.x] = ((const f32x4*)leaf)[threadIdx.x];
  __syncthreads();

  const int lane = threadIdx.x & 63;
  const int wave = threadIdx.x >> 6;
  const int row  = (blockIdx.x * 4 + wave) * 64 + lane;

  // Row into registers, kept both as float2 pairs (for v_pk_fma_f32) and
  // scalars (for the np-exact fixup). All indices constant after unroll.
  f32x2 xr2[32];
  {
    const f32x4* xp = (const f32x4*)(x + (size_t)row * 64);
#pragma unroll
    for (int q = 0; q < 16; ++q) {
      const f32x4 v = xp[q];
      f32x2 h0; h0.x = v.x; h0.y = v.y;
      f32x2 h1; h1.x = v.z; h1.y = v.w;
      xr2[2 * q]     = h0;
      xr2[2 * q + 1] = h1;
    }
  }
  const float* xs = (const float*)xr2;

  uint64_t bits = 0, flag = 0;
#pragma unroll 4
  for (int d = 0; d < 48; ++d) {
    const f32x2* __restrict__ w2 = (const f32x2*)(Wsel + d * 64);  // uniform -> s_load
    f32x2 c0 = {0.f, 0.f}, c1 = {0.f, 0.f}, c2 = {0.f, 0.f}, c3 = {0.f, 0.f};
#pragma unroll
    for (int i = 0; i < 8; ++i) {
      c0 = __builtin_elementwise_fma(xr2[4 * i + 0], w2[4 * i + 0], c0);
      c1 = __builtin_elementwise_fma(xr2[4 * i + 1], w2[4 * i + 1], c1);
      c2 = __builtin_elementwise_fma(xr2[4 * i + 2], w2[4 * i + 2], c2);
      c3 = __builtin_elementwise_fma(xr2[4 * i + 3], w2[4 * i + 3], c3);
    }
    const f32x2 s = (c0 + c1) + (c2 + c3);
    const float z = (s.x + s.y) + bsel[d];
    bits |= (uint64_t)(z > kTau ? 1u : 0u) << d;
    flag |= (uint64_t)(__builtin_fabsf(z - kTau) < kMargin ? 1u : 0u) << d;
  }

  // Divergent fixup: bit-exact np-order recompute of flagged logits only.
  while (flag) {
    const int d = __builtin_ctzll(flag);
    flag &= flag - 1;
    const float z = np_exact_dot(xs, Wsel + d * 64) + bsel[d];
    const uint64_t m = 1ull << d;
    bits = (z > kTau) ? (bits | m) : (bits & ~m);
  }

  // Tree walk (level 0 = MSB), LDS leaf gather, 16->2 FC.
  float o0 = fcb[0], o1 = fcb[1];
#pragma unroll
  for (int t = 0; t < 8; ++t) {
    int idx = 0;
#pragma unroll
    for (int l = 0; l < 6; ++l)
      idx = idx * 2 + (int)((bits >> (t * 6 + l)) & 1u);
    const f32x2 lv = lleaf[t * 64 + idx];
    o0 = fmaf(lv.x, fcw[2 * t], o0);
    o0 = fmaf(lv.y, fcw[2 * t + 1], o0);
    o1 = fmaf(lv.x, fcw[16 + 2 * t], o1);
    o1 = fmaf(lv.y, fcw[16 + 2 * t + 1], o1);
  }
  f32x2 r; r.x = o0; r.y = o1;
  ((f32x2*)out)[row] = r;
}

extern "C" void kernel_launch(void* const* d_in, const int* in_sizes, int n_in,
                              void* d_out, int out_size, void* d_ws, size_t ws_size,
                              hipStream_t stream) {
  (void)in_sizes; (void)n_in; (void)out_size; (void)d_ws; (void)ws_size;
  forest_fast<<<kBlocks, 256, 0, stream>>>(
      (const float*)d_in[0],   // x
      (const float*)d_in[1],   // W_sel
      (const float*)d_in[2],   // b_sel
      (const float*)d_in[3],   // leaf_values
      (const float*)d_in[4],   // fc_w
      (const float*)d_in[5],   // fc_b
      (float*)d_out);
}

// Round 7
// 394.661 us; speedup vs baseline: 1.1888x; 1.0728x over previous
//
#include <hip/hip_runtime.h>
#include <stdint.h>

// NODE forest — fast packed-FMA path + rare np-exact fixup (no scratch).
// Verified semantics (r5 PASS): bit d = (z_np > tau), tau = 1.5*2^-24 (f32
// sigmoid dead-zone), z_np = numpy baseline-SIMD f32 dot order (no FMA,
// reverse-chained muladd, hadd pairing) + bias.
// Round-6 lesson: casting a register array to float* forced xr2 into scratch
// (WRITE_SIZE 270 MB == 1M x 256 B) -> 166 us. This version keeps the row
// purely in registers; the fixup (~4K rows) re-reads x from global (L1-hot).

typedef float f32x2 __attribute__((ext_vector_type(2)));
typedef float f32x4 __attribute__((ext_vector_type(4)));

static constexpr int   kBlocks = 4096;   // x4 waves x64 lanes = 1M rows
static constexpr float kTau    = 1.5f * 0x1p-24f;
static constexpr float kMargin = 1e-4f;  // >=20x max inter-order f32 drift

// Bit-exact replica of numpy's baseline-SIMD einsum f32 order; reads the row
// from GLOBAL memory (cache-hot), so no addressable register array is needed.
__device__ __noinline__ float np_exact_dot(const float* __restrict__ xs,
                                           const float* __restrict__ w) {
#pragma clang fp contract(off)
  float s[4];
#pragma unroll
  for (int L = 0; L < 4; ++L) {
    float t = xs[12 + L] * w[12 + L];
    t = xs[8 + L] * w[8 + L] + t;
    t = xs[4 + L] * w[4 + L] + t;
    t = xs[0 + L] * w[0 + L] + t;
#pragma unroll
    for (int j = 1; j < 4; ++j) {
      const int o = 16 * j;
      t = xs[o + 12 + L] * w[o + 12 + L] + t;
      t = xs[o +  8 + L] * w[o +  8 + L] + t;
      t = xs[o +  4 + L] * w[o +  4 + L] + t;
      t = xs[o +  0 + L] * w[o +  0 + L] + t;
    }
    s[L] = t;
  }
  return (s[0] + s[1]) + (s[2] + s[3]);   // SSE3 hadd pairing
}

__global__ __launch_bounds__(256) void forest_fast(
    const float* __restrict__ x,     // [B,64]
    const float* __restrict__ Wsel,  // [48,64]
    const float* __restrict__ bsel,  // [48]
    const float* __restrict__ leaf,  // [8,64,2]
    const float* __restrict__ fcw,   // [2,16]
    const float* __restrict__ fcb,   // [2]
    float* __restrict__ out)         // [B,2]
{
  __shared__ f32x2 lleaf[512];
  ((f32x4*)lleaf)[threadIdx.x] = ((const f32x4*)leaf)[threadIdx.x];
  __syncthreads();

  const int lane = threadIdx.x & 63;
  const int wave = threadIdx.x >> 6;
  const int row  = (blockIdx.x * 4 + wave) * 64 + lane;
  const float* __restrict__ xrow = x + (size_t)row * 64;

  // Row in registers only (f32x2 pairs for v_pk_fma_f32). No address taken.
  f32x2 xr2[32];
  {
    const f32x4* xp = (const f32x4*)xrow;
#pragma unroll
    for (int q = 0; q < 16; ++q) {
      const f32x4 v = xp[q];
      f32x2 h0; h0.x = v.x; h0.y = v.y;
      f32x2 h1; h1.x = v.z; h1.y = v.w;
      xr2[2 * q]     = h0;
      xr2[2 * q + 1] = h1;
    }
  }

  uint64_t bits = 0, flag = 0;
#pragma unroll 4
  for (int d = 0; d < 48; ++d) {
    const f32x2* __restrict__ w2 = (const f32x2*)(Wsel + d * 64);  // uniform
    f32x2 c0 = {0.f, 0.f}, c1 = {0.f, 0.f}, c2 = {0.f, 0.f}, c3 = {0.f, 0.f};
#pragma unroll
    for (int i = 0; i < 8; ++i) {
      c0 = __builtin_elementwise_fma(xr2[4 * i + 0], w2[4 * i + 0], c0);
      c1 = __builtin_elementwise_fma(xr2[4 * i + 1], w2[4 * i + 1], c1);
      c2 = __builtin_elementwise_fma(xr2[4 * i + 2], w2[4 * i + 2], c2);
      c3 = __builtin_elementwise_fma(xr2[4 * i + 3], w2[4 * i + 3], c3);
    }
    const f32x2 s = (c0 + c1) + (c2 + c3);
    const float z = (s.x + s.y) + bsel[d];
    bits |= (uint64_t)(z > kTau ? 1u : 0u) << d;
    flag |= (uint64_t)(__builtin_fabsf(z - kTau) < kMargin ? 1u : 0u) << d;
  }

  // Divergent fixup: bit-exact np-order recompute of flagged logits only
  // (~0.4% of rows flag at least one d; x row is L1/L2-hot).
  while (flag) {
    const int d = __builtin_ctzll(flag);
    flag &= flag - 1;
    const float z = np_exact_dot(xrow, Wsel + d * 64) + bsel[d];
    const uint64_t m = 1ull << d;
    bits = (z > kTau) ? (bits | m) : (bits & ~m);
  }

  // Tree walk (level 0 = MSB), LDS leaf gather, 16->2 FC.
  float o0 = fcb[0], o1 = fcb[1];
#pragma unroll
  for (int t = 0; t < 8; ++t) {
    int idx = 0;
#pragma unroll
    for (int l = 0; l < 6; ++l)
      idx = idx * 2 + (int)((bits >> (t * 6 + l)) & 1u);
    const f32x2 lv = lleaf[t * 64 + idx];
    o0 = fmaf(lv.x, fcw[2 * t], o0);
    o0 = fmaf(lv.y, fcw[2 * t + 1], o0);
    o1 = fmaf(lv.x, fcw[16 + 2 * t], o1);
    o1 = fmaf(lv.y, fcw[16 + 2 * t + 1], o1);
  }
  f32x2 r; r.x = o0; r.y = o1;
  ((f32x2*)out)[row] = r;
}

extern "C" void kernel_launch(void* const* d_in, const int* in_sizes, int n_in,
                              void* d_out, int out_size, void* d_ws, size_t ws_size,
                              hipStream_t stream) {
  (void)in_sizes; (void)n_in; (void)out_size; (void)d_ws; (void)ws_size;
  forest_fast<<<kBlocks, 256, 0, stream>>>(
      (const float*)d_in[0],   // x
      (const float*)d_in[1],   // W_sel
      (const float*)d_in[2],   // b_sel
      (const float*)d_in[3],   // leaf_values
      (const float*)d_in[4],   // fc_w
      (const float*)d_in[5],   // fc_b
      (float*)d_out);
}